// Round 8
// baseline (929.336 us; speedup 1.0000x reference)
//
#include <hip/hip_runtime.h>

#define N_NODES 100000
#define N_EDGES 1200000
#define NB_SCAN ((N_NODES + 1023) / 1024)   // 98 blocks of 1024 elements
// D_IN = D_HID = 64, D_OUT = 16

// ---------------------------------------------------------------------------
// CSR build: deg histogram -> exclusive scan (3 tiny kernels) -> cursor fill.
// ---------------------------------------------------------------------------
__global__ __launch_bounds__(256) void k_hist(const int* __restrict__ ei,
                                              int* __restrict__ deg) {
    int e = blockIdx.x * 256 + threadIdx.x;
    if (e < N_EDGES) atomicAdd(&deg[ei[N_EDGES + e]], 1);
}

__global__ __launch_bounds__(256) void k_scanA(const int* __restrict__ deg,
                                               int* __restrict__ bsum) {
    const int b = blockIdx.x, t = threadIdx.x;
    const int base = b * 1024 + t * 4;
    int s = 0;
    #pragma unroll
    for (int i = 0; i < 4; ++i) {
        int idx = base + i;
        if (idx < N_NODES) s += deg[idx];
    }
    #pragma unroll
    for (int off = 1; off < 64; off <<= 1) s += __shfl_xor(s, off);
    __shared__ int part[4];
    if ((t & 63) == 0) part[t >> 6] = s;
    __syncthreads();
    if (t == 0) bsum[b] = part[0] + part[1] + part[2] + part[3];
}

__global__ void k_scanB(const int* __restrict__ bsum, int* __restrict__ boff) {
    if (threadIdx.x == 0) {
        int acc = 0;
        for (int i = 0; i < NB_SCAN; ++i) { boff[i] = acc; acc += bsum[i]; }
    }
}

__global__ __launch_bounds__(256) void k_scanC(const int* __restrict__ deg,
                                               const int* __restrict__ boff,
                                               int* __restrict__ row_ptr) {
    __shared__ int tot[256];
    const int b = blockIdx.x, t = threadIdx.x;
    const int base = b * 1024 + t * 4;
    int d[4]; int s = 0;
    #pragma unroll
    for (int i = 0; i < 4; ++i) {
        int idx = base + i;
        d[i] = (idx < N_NODES) ? deg[idx] : 0;
        s += d[i];
    }
    tot[t] = s;
    __syncthreads();
    for (int off = 1; off < 256; off <<= 1) {
        int v = (t >= off) ? tot[t - off] : 0;
        __syncthreads();
        tot[t] += v;
        __syncthreads();
    }
    int run = boff[b] + tot[t] - s;   // exclusive prefix for this thread
    #pragma unroll
    for (int i = 0; i < 4; ++i) {
        int idx = base + i;
        if (idx < N_NODES) { row_ptr[idx] = run; run += d[i]; }
    }
    if (b == 0 && t == 0) row_ptr[N_NODES] = N_EDGES;
}

__global__ __launch_bounds__(256) void k_fill(const int* __restrict__ ei,
                                              const float* __restrict__ ew,
                                              int* __restrict__ cursor,
                                              uint2* __restrict__ csr) {
    int e = blockIdx.x * 256 + threadIdx.x;
    if (e < N_EDGES) {
        int src = ei[e];
        int dst = ei[N_EDGES + e];
        int pos = atomicAdd(&cursor[dst], 1);
        csr[pos] = make_uint2((unsigned)src, __float_as_uint(ew[e]));
    }
}

// ---------------------------------------------------------------------------
// k_l1: fused layer-1 gather + node update (wave per dst node, lane = dim).
// Gather keeps the round-4 access shape that kept EA traffic at 148 MB:
// wave-uniform src row (readlane -> SGPR base) + lane-contiguous 256B load.
// MLP fix: 4 independent accumulators, 4 edges' row-loads issued together
// (4 outstanding per wave) instead of a serial load->fma chain.
// Then: h = relu(mean@W1l + x[n]@W1r + b1); z2 = h@W2l; hw2r = h@W2r.
// ---------------------------------------------------------------------------
__global__ __launch_bounds__(512, 6) void k_l1(const float* __restrict__ x,
                                               const int* __restrict__ row_ptr,
                                               const uint2* __restrict__ csr,
                                               const float* __restrict__ W1l,
                                               const float* __restrict__ b1,
                                               const float* __restrict__ W1r,
                                               const float* __restrict__ W2l,
                                               const float* __restrict__ W2r,
                                               float* __restrict__ z2,
                                               float* __restrict__ hw2r) {
    __shared__ float w1l[64 * 64];
    __shared__ float w1r[64 * 64];
    __shared__ float w2l[64 * 17];   // stride-17: 4-way bank conflict -> 2-way
    __shared__ float w2r[64 * 17];
    for (int i = threadIdx.x; i < 64 * 64; i += 512) { w1l[i] = W1l[i]; w1r[i] = W1r[i]; }
    for (int i = threadIdx.x; i < 64 * 16; i += 512) {
        int k = i >> 4, j = i & 15;
        w2l[k * 17 + j] = W2l[i];
        w2r[k * 17 + j] = W2r[i];
    }
    __syncthreads();
    const int lane = threadIdx.x & 63;
    const int wid  = blockIdx.x * 8 + (threadIdx.x >> 6);
    const int nw   = gridDim.x * 8;
    const int j = lane & 15, g = lane >> 4;
    const float b1v = b1[lane];              // bias in reg (not LDS)
    for (int n = wid; n < N_NODES; n += nw) {
        const int r0 = row_ptr[n], r1 = row_ptr[n + 1];
        const int deg = r1 - r0;
        float acc0 = 0.f, acc1 = 0.f, acc2 = 0.f, acc3 = 0.f;
        for (int base = r0; base < r1; base += 64) {
            const int m = r1 - base < 64 ? r1 - base : 64;
            uint2 sw = make_uint2(0u, 0u);
            if (lane < m) sw = csr[base + lane];        // coalesced metadata
            const int sv = (int)sw.x;
            const int wv = (int)sw.y;
            int it = 0;
            for (; it + 4 <= m; it += 4) {
                int s0 = __builtin_amdgcn_readlane(sv, it);
                int s1 = __builtin_amdgcn_readlane(sv, it + 1);
                int s2 = __builtin_amdgcn_readlane(sv, it + 2);
                int s3 = __builtin_amdgcn_readlane(sv, it + 3);
                float w0 = __int_as_float(__builtin_amdgcn_readlane(wv, it));
                float w1 = __int_as_float(__builtin_amdgcn_readlane(wv, it + 1));
                float w2 = __int_as_float(__builtin_amdgcn_readlane(wv, it + 2));
                float w3 = __int_as_float(__builtin_amdgcn_readlane(wv, it + 3));
                // 4 independent wave-wide 256B gathers -> 4 outstanding loads
                float v0 = x[(size_t)s0 * 64 + lane];
                float v1 = x[(size_t)s1 * 64 + lane];
                float v2 = x[(size_t)s2 * 64 + lane];
                float v3 = x[(size_t)s3 * 64 + lane];
                acc0 = fmaf(v0, w0, acc0);
                acc1 = fmaf(v1, w1, acc1);
                acc2 = fmaf(v2, w2, acc2);
                acc3 = fmaf(v3, w3, acc3);
            }
            for (; it < m; ++it) {
                int   s = __builtin_amdgcn_readlane(sv, it);
                float w = __int_as_float(__builtin_amdgcn_readlane(wv, it));
                acc0 = fmaf(x[(size_t)s * 64 + lane], w, acc0);
            }
        }
        const float acc = (acc0 + acc1) + (acc2 + acc3);
        const float inv = 1.f / (float)(deg > 0 ? deg : 1);
        const float av  = acc * inv;            // mean neighbor feature
        const float xr  = x[(size_t)n * 64 + lane];
        float hacc = b1v;
        #pragma unroll
        for (int k = 0; k < 64; ++k) {
            float ak = __shfl(av, k);
            float xk = __shfl(xr, k);
            hacc = fmaf(ak, w1l[k * 64 + lane], hacc);
            hacc = fmaf(xk, w1r[k * 64 + lane], hacc);
        }
        const float hval = hacc > 0.f ? hacc : 0.f;   // ReLU, stays in regs

        // z2 = h @ W2l, hw2r = h @ W2r (16 outs; groups split k, xor-combine)
        float azv = 0.f, arv = 0.f;
        #pragma unroll
        for (int i = 0; i < 16; ++i) {
            int   k  = g * 16 + i;
            float hk = __shfl(hval, k);
            azv = fmaf(hk, w2l[k * 17 + j], azv);
            arv = fmaf(hk, w2r[k * 17 + j], arv);
        }
        azv += __shfl_xor(azv, 16); azv += __shfl_xor(azv, 32);
        arv += __shfl_xor(arv, 16); arv += __shfl_xor(arv, 32);
        if (g == 0) {
            z2[(size_t)n * 16 + j]   = azv;
            hw2r[(size_t)n * 16 + j] = arv;
        }
    }
}

// ---------------------------------------------------------------------------
// k_l2: fused layer-2 gather + epilogue (wave per dst node).
// 4 lane-groups of 16; group g takes edges r0+g, r0+g+4, ...; metadata is
// group-uniform (broadcast load), z2 row read is 16-lane contiguous 64B.
// Unroll-2 -> 8 outstanding 64B gathers per wave. xor-combine groups.
//   out[n][j] = (sum z2[src][j]*w)/max(deg,1) + b2[j] + hw2r[n][j]
// ---------------------------------------------------------------------------
__global__ __launch_bounds__(256) void k_l2(const float* __restrict__ z2,
                                            const int* __restrict__ row_ptr,
                                            const uint2* __restrict__ csr,
                                            const float* __restrict__ b2,
                                            const float* __restrict__ hw2r,
                                            float* __restrict__ out) {
    const int lane = threadIdx.x & 63;
    const int wid  = blockIdx.x * 4 + (threadIdx.x >> 6);
    const int nw   = gridDim.x * 4;
    const int j = lane & 15, g = lane >> 4;
    for (int n = wid; n < N_NODES; n += nw) {
        const int r0 = row_ptr[n], r1 = row_ptr[n + 1];
        const int deg = r1 - r0;
        float a = 0.f;
        int i = r0 + g;
        for (; i + 4 < r1; i += 8) {            // edges i and i+4 together
            uint2 e0 = csr[i];
            uint2 e1 = csr[i + 4];
            float z0 = z2[(size_t)e0.x * 16 + j];
            float z1 = z2[(size_t)e1.x * 16 + j];
            a = fmaf(z0, __uint_as_float(e0.y), a);
            a = fmaf(z1, __uint_as_float(e1.y), a);
        }
        if (i < r1) {
            uint2 e0 = csr[i];
            a = fmaf(z2[(size_t)e0.x * 16 + j], __uint_as_float(e0.y), a);
        }
        a += __shfl_xor(a, 16); a += __shfl_xor(a, 32);
        if (g == 0) {
            const float inv = 1.f / (float)(deg > 0 ? deg : 1);
            out[(size_t)n * 16 + j] = a * inv + b2[j] + hw2r[(size_t)n * 16 + j];
        }
    }
}

extern "C" void kernel_launch(void* const* d_in, const int* in_sizes, int n_in,
                              void* d_out, int out_size, void* d_ws, size_t ws_size,
                              hipStream_t stream) {
    const float* x   = (const float*)d_in[0];
    const int*   ei  = (const int*)d_in[1];   // [2, E]: row0=src, row1=dst
    const float* ew  = (const float*)d_in[2];
    const float* W1l = (const float*)d_in[3];
    const float* b1  = (const float*)d_in[4];
    const float* W1r = (const float*)d_in[5];
    const float* W2l = (const float*)d_in[6];
    const float* b2  = (const float*)d_in[7];
    const float* W2r = (const float*)d_in[8];
    float* out = (float*)d_out;

    // Workspace layout (csr first: 8B alignment at base).
    char* w = (char*)d_ws;
    uint2* csr     = (uint2*)w;  w += (size_t)N_EDGES * 8;
    float* z2      = (float*)w;  w += (size_t)N_NODES * 16 * 4;
    float* hw2r    = (float*)w;  w += (size_t)N_NODES * 16 * 4;
    int*   deg     = (int*)w;    w += (size_t)N_NODES * 4;
    int*   row_ptr = (int*)w;    w += (size_t)(N_NODES + 1) * 4;
    int*   cursor  = (int*)w;    w += (size_t)N_NODES * 4;
    int*   bsum    = (int*)w;    w += 128 * 4;
    int*   boff    = (int*)w;

    hipMemsetAsync(deg, 0, (size_t)N_NODES * 4, stream);

    k_hist <<<(N_EDGES + 255) / 256, 256, 0, stream>>>(ei, deg);
    k_scanA<<<NB_SCAN, 256, 0, stream>>>(deg, bsum);
    k_scanB<<<1, 64, 0, stream>>>(bsum, boff);
    k_scanC<<<NB_SCAN, 256, 0, stream>>>(deg, boff, row_ptr);
    hipMemcpyAsync(cursor, row_ptr, (size_t)N_NODES * 4,
                   hipMemcpyDeviceToDevice, stream);
    k_fill <<<(N_EDGES + 255) / 256, 256, 0, stream>>>(ei, ew, cursor, csr);
    k_l1   <<<1024, 512, 0, stream>>>(x, row_ptr, csr, W1l, b1, W1r, W2l, W2r, z2, hw2r);
    k_l2   <<<1024, 256, 0, stream>>>(z2, row_ptr, csr, b2, hw2r, out);
}

// Round 9
// 530.765 us; speedup vs baseline: 1.7509x; 1.7509x over previous
//
#include <hip/hip_runtime.h>

#define N_NODES 100000
#define N_EDGES 1200000
#define NB_SCAN ((N_NODES + 1023) / 1024)   // 98 blocks of 1024 elements
// D_IN = D_HID = 64, D_OUT = 16

// ---------------------------------------------------------------------------
// CSR build: deg histogram -> exclusive scan (3 tiny kernels) -> cursor fill.
// ---------------------------------------------------------------------------
__global__ __launch_bounds__(256) void k_hist(const int* __restrict__ ei,
                                              int* __restrict__ deg) {
    int e = blockIdx.x * 256 + threadIdx.x;
    if (e < N_EDGES) atomicAdd(&deg[ei[N_EDGES + e]], 1);
}

__global__ __launch_bounds__(256) void k_scanA(const int* __restrict__ deg,
                                               int* __restrict__ bsum) {
    const int b = blockIdx.x, t = threadIdx.x;
    const int base = b * 1024 + t * 4;
    int s = 0;
    #pragma unroll
    for (int i = 0; i < 4; ++i) {
        int idx = base + i;
        if (idx < N_NODES) s += deg[idx];
    }
    #pragma unroll
    for (int off = 1; off < 64; off <<= 1) s += __shfl_xor(s, off);
    __shared__ int part[4];
    if ((t & 63) == 0) part[t >> 6] = s;
    __syncthreads();
    if (t == 0) bsum[b] = part[0] + part[1] + part[2] + part[3];
}

__global__ void k_scanB(const int* __restrict__ bsum, int* __restrict__ boff) {
    if (threadIdx.x == 0) {
        int acc = 0;
        for (int i = 0; i < NB_SCAN; ++i) { boff[i] = acc; acc += bsum[i]; }
    }
}

__global__ __launch_bounds__(256) void k_scanC(const int* __restrict__ deg,
                                               const int* __restrict__ boff,
                                               int* __restrict__ row_ptr) {
    __shared__ int tot[256];
    const int b = blockIdx.x, t = threadIdx.x;
    const int base = b * 1024 + t * 4;
    int d[4]; int s = 0;
    #pragma unroll
    for (int i = 0; i < 4; ++i) {
        int idx = base + i;
        d[i] = (idx < N_NODES) ? deg[idx] : 0;
        s += d[i];
    }
    tot[t] = s;
    __syncthreads();
    for (int off = 1; off < 256; off <<= 1) {
        int v = (t >= off) ? tot[t - off] : 0;
        __syncthreads();
        tot[t] += v;
        __syncthreads();
    }
    int run = boff[b] + tot[t] - s;   // exclusive prefix for this thread
    #pragma unroll
    for (int i = 0; i < 4; ++i) {
        int idx = base + i;
        if (idx < N_NODES) { row_ptr[idx] = run; run += d[i]; }
    }
    if (b == 0 && t == 0) row_ptr[N_NODES] = N_EDGES;
}

__global__ __launch_bounds__(256) void k_fill(const int* __restrict__ ei,
                                              const float* __restrict__ ew,
                                              int* __restrict__ cursor,
                                              uint2* __restrict__ csr) {
    int e = blockIdx.x * 256 + threadIdx.x;
    if (e < N_EDGES) {
        int src = ei[e];
        int dst = ei[N_EDGES + e];
        int pos = atomicAdd(&cursor[dst], 1);
        csr[pos] = make_uint2((unsigned)src, __float_as_uint(ew[e]));
    }
}

// ---------------------------------------------------------------------------
// k_l1: fused layer-1 gather + node update (wave per dst node, lane = dim).
// Wave-uniform src row (readlane -> SGPR base) + lane-contiguous 256B load;
// 4 independent accumulators keep 4 gathers outstanding per wave.
// __launch_bounds__(512,2): VGPR cap 256 -> NO SPILLS. (512,6) capped VGPR
// at ~85 and spilled the inner loop to scratch: WRITE_SIZE 237MB vs 13MB
// logical, FETCH 1.5GB, 2x slowdown. Occupancy comes from natural VGPR use
// (<=128 -> 16 waves/CU with 512-thread blocks), not from a forced cap.
// Then: h = relu(mean@W1l + x[n]@W1r + b1); z2 = h@W2l; hw2r = h@W2r.
// ---------------------------------------------------------------------------
__global__ __launch_bounds__(512, 2) void k_l1(const float* __restrict__ x,
                                               const int* __restrict__ row_ptr,
                                               const uint2* __restrict__ csr,
                                               const float* __restrict__ W1l,
                                               const float* __restrict__ b1,
                                               const float* __restrict__ W1r,
                                               const float* __restrict__ W2l,
                                               const float* __restrict__ W2r,
                                               float* __restrict__ z2,
                                               float* __restrict__ hw2r) {
    __shared__ float w1l[64 * 64];
    __shared__ float w1r[64 * 64];
    __shared__ float w2l[64 * 17];   // stride-17: 4-way bank conflict -> 2-way
    __shared__ float w2r[64 * 17];
    for (int i = threadIdx.x; i < 64 * 64; i += 512) { w1l[i] = W1l[i]; w1r[i] = W1r[i]; }
    for (int i = threadIdx.x; i < 64 * 16; i += 512) {
        int k = i >> 4, j = i & 15;
        w2l[k * 17 + j] = W2l[i];
        w2r[k * 17 + j] = W2r[i];
    }
    __syncthreads();
    const int lane = threadIdx.x & 63;
    const int wid  = blockIdx.x * 8 + (threadIdx.x >> 6);
    const int nw   = gridDim.x * 8;
    const int j = lane & 15, g = lane >> 4;
    const float b1v = b1[lane];              // bias in reg (not LDS)
    for (int n = wid; n < N_NODES; n += nw) {
        const int r0 = row_ptr[n], r1 = row_ptr[n + 1];
        const int deg = r1 - r0;
        float acc0 = 0.f, acc1 = 0.f, acc2 = 0.f, acc3 = 0.f;
        for (int base = r0; base < r1; base += 64) {
            const int m = r1 - base < 64 ? r1 - base : 64;
            uint2 sw = make_uint2(0u, 0u);
            if (lane < m) sw = csr[base + lane];        // coalesced metadata
            const int sv = (int)sw.x;
            const int wv = (int)sw.y;
            int it = 0;
            for (; it + 4 <= m; it += 4) {
                int s0 = __builtin_amdgcn_readlane(sv, it);
                int s1 = __builtin_amdgcn_readlane(sv, it + 1);
                int s2 = __builtin_amdgcn_readlane(sv, it + 2);
                int s3 = __builtin_amdgcn_readlane(sv, it + 3);
                float w0 = __int_as_float(__builtin_amdgcn_readlane(wv, it));
                float w1 = __int_as_float(__builtin_amdgcn_readlane(wv, it + 1));
                float w2 = __int_as_float(__builtin_amdgcn_readlane(wv, it + 2));
                float w3 = __int_as_float(__builtin_amdgcn_readlane(wv, it + 3));
                // 4 independent wave-wide 256B gathers -> 4 outstanding loads
                float v0 = x[(size_t)s0 * 64 + lane];
                float v1 = x[(size_t)s1 * 64 + lane];
                float v2 = x[(size_t)s2 * 64 + lane];
                float v3 = x[(size_t)s3 * 64 + lane];
                acc0 = fmaf(v0, w0, acc0);
                acc1 = fmaf(v1, w1, acc1);
                acc2 = fmaf(v2, w2, acc2);
                acc3 = fmaf(v3, w3, acc3);
            }
            for (; it < m; ++it) {
                int   s = __builtin_amdgcn_readlane(sv, it);
                float w = __int_as_float(__builtin_amdgcn_readlane(wv, it));
                acc0 = fmaf(x[(size_t)s * 64 + lane], w, acc0);
            }
        }
        const float acc = (acc0 + acc1) + (acc2 + acc3);
        const float inv = 1.f / (float)(deg > 0 ? deg : 1);
        const float av  = acc * inv;            // mean neighbor feature
        const float xr  = x[(size_t)n * 64 + lane];
        float hacc = b1v;
        #pragma unroll
        for (int k = 0; k < 64; ++k) {
            float ak = __shfl(av, k);
            float xk = __shfl(xr, k);
            hacc = fmaf(ak, w1l[k * 64 + lane], hacc);
            hacc = fmaf(xk, w1r[k * 64 + lane], hacc);
        }
        const float hval = hacc > 0.f ? hacc : 0.f;   // ReLU, stays in regs

        // z2 = h @ W2l, hw2r = h @ W2r (16 outs; groups split k, xor-combine)
        float azv = 0.f, arv = 0.f;
        #pragma unroll
        for (int i = 0; i < 16; ++i) {
            int   k  = g * 16 + i;
            float hk = __shfl(hval, k);
            azv = fmaf(hk, w2l[k * 17 + j], azv);
            arv = fmaf(hk, w2r[k * 17 + j], arv);
        }
        azv += __shfl_xor(azv, 16); azv += __shfl_xor(azv, 32);
        arv += __shfl_xor(arv, 16); arv += __shfl_xor(arv, 32);
        if (g == 0) {
            z2[(size_t)n * 16 + j]   = azv;
            hw2r[(size_t)n * 16 + j] = arv;
        }
    }
}

// ---------------------------------------------------------------------------
// k_l2: fused layer-2 gather + epilogue (wave per dst node).
// 4 lane-groups of 16; group g takes edges r0+g, r0+g+4, ...; metadata is
// group-uniform (broadcast load), z2 row read is 16-lane contiguous 64B.
// Unroll-2 -> 8 outstanding 64B gathers per wave. xor-combine groups.
//   out[n][j] = (sum z2[src][j]*w)/max(deg,1) + b2[j] + hw2r[n][j]
// ---------------------------------------------------------------------------
__global__ __launch_bounds__(256) void k_l2(const float* __restrict__ z2,
                                            const int* __restrict__ row_ptr,
                                            const uint2* __restrict__ csr,
                                            const float* __restrict__ b2,
                                            const float* __restrict__ hw2r,
                                            float* __restrict__ out) {
    const int lane = threadIdx.x & 63;
    const int wid  = blockIdx.x * 4 + (threadIdx.x >> 6);
    const int nw   = gridDim.x * 4;
    const int j = lane & 15, g = lane >> 4;
    for (int n = wid; n < N_NODES; n += nw) {
        const int r0 = row_ptr[n], r1 = row_ptr[n + 1];
        const int deg = r1 - r0;
        float a = 0.f;
        int i = r0 + g;
        for (; i + 4 < r1; i += 8) {            // edges i and i+4 together
            uint2 e0 = csr[i];
            uint2 e1 = csr[i + 4];
            float z0 = z2[(size_t)e0.x * 16 + j];
            float z1 = z2[(size_t)e1.x * 16 + j];
            a = fmaf(z0, __uint_as_float(e0.y), a);
            a = fmaf(z1, __uint_as_float(e1.y), a);
        }
        if (i < r1) {
            uint2 e0 = csr[i];
            a = fmaf(z2[(size_t)e0.x * 16 + j], __uint_as_float(e0.y), a);
        }
        a += __shfl_xor(a, 16); a += __shfl_xor(a, 32);
        if (g == 0) {
            const float inv = 1.f / (float)(deg > 0 ? deg : 1);
            out[(size_t)n * 16 + j] = a * inv + b2[j] + hw2r[(size_t)n * 16 + j];
        }
    }
}

extern "C" void kernel_launch(void* const* d_in, const int* in_sizes, int n_in,
                              void* d_out, int out_size, void* d_ws, size_t ws_size,
                              hipStream_t stream) {
    const float* x   = (const float*)d_in[0];
    const int*   ei  = (const int*)d_in[1];   // [2, E]: row0=src, row1=dst
    const float* ew  = (const float*)d_in[2];
    const float* W1l = (const float*)d_in[3];
    const float* b1  = (const float*)d_in[4];
    const float* W1r = (const float*)d_in[5];
    const float* W2l = (const float*)d_in[6];
    const float* b2  = (const float*)d_in[7];
    const float* W2r = (const float*)d_in[8];
    float* out = (float*)d_out;

    // Workspace layout (csr first: 8B alignment at base).
    char* w = (char*)d_ws;
    uint2* csr     = (uint2*)w;  w += (size_t)N_EDGES * 8;
    float* z2      = (float*)w;  w += (size_t)N_NODES * 16 * 4;
    float* hw2r    = (float*)w;  w += (size_t)N_NODES * 16 * 4;
    int*   deg     = (int*)w;    w += (size_t)N_NODES * 4;
    int*   row_ptr = (int*)w;    w += (size_t)(N_NODES + 1) * 4;
    int*   cursor  = (int*)w;    w += (size_t)N_NODES * 4;
    int*   bsum    = (int*)w;    w += 128 * 4;
    int*   boff    = (int*)w;

    hipMemsetAsync(deg, 0, (size_t)N_NODES * 4, stream);

    k_hist <<<(N_EDGES + 255) / 256, 256, 0, stream>>>(ei, deg);
    k_scanA<<<NB_SCAN, 256, 0, stream>>>(deg, bsum);
    k_scanB<<<1, 64, 0, stream>>>(bsum, boff);
    k_scanC<<<NB_SCAN, 256, 0, stream>>>(deg, boff, row_ptr);
    hipMemcpyAsync(cursor, row_ptr, (size_t)N_NODES * 4,
                   hipMemcpyDeviceToDevice, stream);
    k_fill <<<(N_EDGES + 255) / 256, 256, 0, stream>>>(ei, ew, cursor, csr);
    k_l1   <<<1024, 512, 0, stream>>>(x, row_ptr, csr, W1l, b1, W1r, W2l, W2r, z2, hw2r);
    k_l2   <<<1024, 256, 0, stream>>>(z2, row_ptr, csr, b2, hw2r, out);
}

// Round 10
// 485.547 us; speedup vs baseline: 1.9140x; 1.0931x over previous
//
#include <hip/hip_runtime.h>

#define N_NODES 100000
#define N_EDGES 1200000
#define NB_SCAN ((N_NODES + 1023) / 1024)   // 98 blocks of 1024 elements
// D_IN = D_HID = 64, D_OUT = 16

// ---------------------------------------------------------------------------
// CSR build: deg histogram -> exclusive scan (3 tiny kernels) -> cursor fill.
// ---------------------------------------------------------------------------
__global__ __launch_bounds__(256) void k_hist(const int* __restrict__ ei,
                                              int* __restrict__ deg) {
    int e = blockIdx.x * 256 + threadIdx.x;
    if (e < N_EDGES) atomicAdd(&deg[ei[N_EDGES + e]], 1);
}

__global__ __launch_bounds__(256) void k_scanA(const int* __restrict__ deg,
                                               int* __restrict__ bsum) {
    const int b = blockIdx.x, t = threadIdx.x;
    const int base = b * 1024 + t * 4;
    int s = 0;
    #pragma unroll
    for (int i = 0; i < 4; ++i) {
        int idx = base + i;
        if (idx < N_NODES) s += deg[idx];
    }
    #pragma unroll
    for (int off = 1; off < 64; off <<= 1) s += __shfl_xor(s, off);
    __shared__ int part[4];
    if ((t & 63) == 0) part[t >> 6] = s;
    __syncthreads();
    if (t == 0) bsum[b] = part[0] + part[1] + part[2] + part[3];
}

__global__ void k_scanB(const int* __restrict__ bsum, int* __restrict__ boff) {
    if (threadIdx.x == 0) {
        int acc = 0;
        for (int i = 0; i < NB_SCAN; ++i) { boff[i] = acc; acc += bsum[i]; }
    }
}

__global__ __launch_bounds__(256) void k_scanC(const int* __restrict__ deg,
                                               const int* __restrict__ boff,
                                               int* __restrict__ row_ptr,
                                               int* __restrict__ cursor) {
    __shared__ int tot[256];
    const int b = blockIdx.x, t = threadIdx.x;
    const int base = b * 1024 + t * 4;
    int d[4]; int s = 0;
    #pragma unroll
    for (int i = 0; i < 4; ++i) {
        int idx = base + i;
        d[i] = (idx < N_NODES) ? deg[idx] : 0;
        s += d[i];
    }
    tot[t] = s;
    __syncthreads();
    for (int off = 1; off < 256; off <<= 1) {
        int v = (t >= off) ? tot[t - off] : 0;
        __syncthreads();
        tot[t] += v;
        __syncthreads();
    }
    int run = boff[b] + tot[t] - s;   // exclusive prefix for this thread
    #pragma unroll
    for (int i = 0; i < 4; ++i) {
        int idx = base + i;
        if (idx < N_NODES) { row_ptr[idx] = run; cursor[idx] = run; run += d[i]; }
    }
    if (b == 0 && t == 0) row_ptr[N_NODES] = N_EDGES;
}

__global__ __launch_bounds__(256) void k_fill(const int* __restrict__ ei,
                                              const float* __restrict__ ew,
                                              int* __restrict__ cursor,
                                              uint2* __restrict__ csr) {
    int e = blockIdx.x * 256 + threadIdx.x;
    if (e < N_EDGES) {
        int src = ei[e];
        int dst = ei[N_EDGES + e];
        int pos = atomicAdd(&cursor[dst], 1);
        csr[pos] = make_uint2((unsigned)src, __float_as_uint(ew[e]));
    }
}

// ---------------------------------------------------------------------------
// k_gather: av[n][d] = (sum_{in-edges} x[src][d]*w_e) / max(deg,1)
// De-fused from the node update so this latency-bound phase runs at high
// occupancy: no LDS, low VGPR -> 8 waves/SIMD (vs 22% when fused with the
// 128-VGPR/41KB-LDS compute). Wave-uniform src row (readlane -> SGPR base)
// + lane-contiguous 256B load, ILP-4 via independent accumulators.
// NO min-waves clause: forcing it caused scratch spills (FETCH 1.5GB).
// ---------------------------------------------------------------------------
__global__ __launch_bounds__(256) void k_gather(const float* __restrict__ x,
                                                const int* __restrict__ row_ptr,
                                                const uint2* __restrict__ csr,
                                                float* __restrict__ av) {
    const int lane = threadIdx.x & 63;
    const int wid  = blockIdx.x * 4 + (threadIdx.x >> 6);
    const int nw   = gridDim.x * 4;
    for (int n = wid; n < N_NODES; n += nw) {
        const int r0 = row_ptr[n], r1 = row_ptr[n + 1];
        const int deg = r1 - r0;
        float acc0 = 0.f, acc1 = 0.f, acc2 = 0.f, acc3 = 0.f;
        for (int base = r0; base < r1; base += 64) {
            const int m = r1 - base < 64 ? r1 - base : 64;
            uint2 sw = make_uint2(0u, 0u);
            if (lane < m) sw = csr[base + lane];        // coalesced metadata
            const int sv = (int)sw.x;
            const int wv = (int)sw.y;
            int it = 0;
            for (; it + 4 <= m; it += 4) {
                int s0 = __builtin_amdgcn_readlane(sv, it);
                int s1 = __builtin_amdgcn_readlane(sv, it + 1);
                int s2 = __builtin_amdgcn_readlane(sv, it + 2);
                int s3 = __builtin_amdgcn_readlane(sv, it + 3);
                float w0 = __int_as_float(__builtin_amdgcn_readlane(wv, it));
                float w1 = __int_as_float(__builtin_amdgcn_readlane(wv, it + 1));
                float w2 = __int_as_float(__builtin_amdgcn_readlane(wv, it + 2));
                float w3 = __int_as_float(__builtin_amdgcn_readlane(wv, it + 3));
                // 4 independent wave-wide 256B gathers -> 4 outstanding loads
                float v0 = x[(size_t)s0 * 64 + lane];
                float v1 = x[(size_t)s1 * 64 + lane];
                float v2 = x[(size_t)s2 * 64 + lane];
                float v3 = x[(size_t)s3 * 64 + lane];
                acc0 = fmaf(v0, w0, acc0);
                acc1 = fmaf(v1, w1, acc1);
                acc2 = fmaf(v2, w2, acc2);
                acc3 = fmaf(v3, w3, acc3);
            }
            for (; it < m; ++it) {
                int   s = __builtin_amdgcn_readlane(sv, it);
                float w = __int_as_float(__builtin_amdgcn_readlane(wv, it));
                acc0 = fmaf(x[(size_t)s * 64 + lane], w, acc0);
            }
        }
        const float acc = (acc0 + acc1) + (acc2 + acc3);
        const float inv = 1.f / (float)(deg > 0 ? deg : 1);
        av[(size_t)n * 64 + lane] = acc * inv;          // coalesced 256B store
    }
}

// ---------------------------------------------------------------------------
// k_node: dense per-node compute (wave per node, lane = dim). Pure VALU:
//   h[d]   = relu(av[n] @ W1l + x[n] @ W1r + b1)[d]    (in registers)
//   z2[j]  = (h @ W2l)[j],  hw2r[j] = (h @ W2r)[j]     (j in 0..15)
// High VGPR/LDS is harmless here (compute-bound, not latency-bound).
// ---------------------------------------------------------------------------
__global__ __launch_bounds__(512) void k_node(const float* __restrict__ x,
                                              const float* __restrict__ av,
                                              const float* __restrict__ W1l,
                                              const float* __restrict__ b1,
                                              const float* __restrict__ W1r,
                                              const float* __restrict__ W2l,
                                              const float* __restrict__ W2r,
                                              float* __restrict__ z2,
                                              float* __restrict__ hw2r) {
    __shared__ float w1l[64 * 64];
    __shared__ float w1r[64 * 64];
    __shared__ float w2l[64 * 17];   // stride-17: 4-way bank conflict -> 2-way
    __shared__ float w2r[64 * 17];
    for (int i = threadIdx.x; i < 64 * 64; i += 512) { w1l[i] = W1l[i]; w1r[i] = W1r[i]; }
    for (int i = threadIdx.x; i < 64 * 16; i += 512) {
        int k = i >> 4, j = i & 15;
        w2l[k * 17 + j] = W2l[i];
        w2r[k * 17 + j] = W2r[i];
    }
    __syncthreads();
    const int lane = threadIdx.x & 63;
    const int wid  = blockIdx.x * 8 + (threadIdx.x >> 6);
    const int nw   = gridDim.x * 8;
    const int j = lane & 15, g = lane >> 4;
    const float b1v = b1[lane];
    for (int n = wid; n < N_NODES; n += nw) {
        const float avv = av[(size_t)n * 64 + lane];
        const float xr  = x[(size_t)n * 64 + lane];
        float hacc = b1v;
        #pragma unroll
        for (int k = 0; k < 64; ++k) {
            float ak = __shfl(avv, k);
            float xk = __shfl(xr, k);
            hacc = fmaf(ak, w1l[k * 64 + lane], hacc);
            hacc = fmaf(xk, w1r[k * 64 + lane], hacc);
        }
        const float hval = hacc > 0.f ? hacc : 0.f;   // ReLU, stays in regs

        // z2 = h @ W2l, hw2r = h @ W2r (16 outs; groups split k, xor-combine)
        float azv = 0.f, arv = 0.f;
        #pragma unroll
        for (int i = 0; i < 16; ++i) {
            int   k  = g * 16 + i;
            float hk = __shfl(hval, k);
            azv = fmaf(hk, w2l[k * 17 + j], azv);
            arv = fmaf(hk, w2r[k * 17 + j], arv);
        }
        azv += __shfl_xor(azv, 16); azv += __shfl_xor(azv, 32);
        arv += __shfl_xor(arv, 16); arv += __shfl_xor(arv, 32);
        if (g == 0) {
            z2[(size_t)n * 16 + j]   = azv;
            hw2r[(size_t)n * 16 + j] = arv;
        }
    }
}

// ---------------------------------------------------------------------------
// k_l2: fused layer-2 gather + epilogue (wave per dst node).
// 4 lane-groups of 16; group g owns edges r0+g+4t. Unroll-4 (clamped index +
// zero weight, statically indexed arrays) -> 16 outstanding 64B gathers/wave.
//   out[n][j] = (sum z2[src][j]*w)/max(deg,1) + b2[j] + hw2r[n][j]
// ---------------------------------------------------------------------------
__global__ __launch_bounds__(256) void k_l2(const float* __restrict__ z2,
                                            const int* __restrict__ row_ptr,
                                            const uint2* __restrict__ csr,
                                            const float* __restrict__ b2,
                                            const float* __restrict__ hw2r,
                                            float* __restrict__ out) {
    const int lane = threadIdx.x & 63;
    const int wid  = blockIdx.x * 4 + (threadIdx.x >> 6);
    const int nw   = gridDim.x * 4;
    const int j = lane & 15, g = lane >> 4;
    for (int n = wid; n < N_NODES; n += nw) {
        const int r0 = row_ptr[n], r1 = row_ptr[n + 1];
        const int deg = r1 - r0;
        const int rmax = r1 - 1;
        float a = 0.f;
        for (int i0 = r0 + g; i0 < r1; i0 += 16) {
            uint2 e[4]; float wt[4];
            #pragma unroll
            for (int u = 0; u < 4; ++u) {
                int idx = i0 + u * 4;
                int idc = idx < rmax ? idx : rmax;   // clamp: valid address
                e[u]  = csr[idc];
                wt[u] = (idx < r1) ? __uint_as_float(e[u].y) : 0.f;
            }
            float zv[4];
            #pragma unroll
            for (int u = 0; u < 4; ++u)
                zv[u] = z2[(size_t)e[u].x * 16 + j];
            #pragma unroll
            for (int u = 0; u < 4; ++u) a = fmaf(zv[u], wt[u], a);
        }
        a += __shfl_xor(a, 16); a += __shfl_xor(a, 32);
        if (g == 0) {
            const float inv = 1.f / (float)(deg > 0 ? deg : 1);
            out[(size_t)n * 16 + j] = a * inv + b2[j] + hw2r[(size_t)n * 16 + j];
        }
    }
}

extern "C" void kernel_launch(void* const* d_in, const int* in_sizes, int n_in,
                              void* d_out, int out_size, void* d_ws, size_t ws_size,
                              hipStream_t stream) {
    const float* x   = (const float*)d_in[0];
    const int*   ei  = (const int*)d_in[1];   // [2, E]: row0=src, row1=dst
    const float* ew  = (const float*)d_in[2];
    const float* W1l = (const float*)d_in[3];
    const float* b1  = (const float*)d_in[4];
    const float* W1r = (const float*)d_in[5];
    const float* W2l = (const float*)d_in[6];
    const float* b2  = (const float*)d_in[7];
    const float* W2r = (const float*)d_in[8];
    float* out = (float*)d_out;

    // Workspace layout (csr first: 8B alignment at base).
    char* w = (char*)d_ws;
    uint2* csr     = (uint2*)w;  w += (size_t)N_EDGES * 8;            // 9.6 MB
    float* av      = (float*)w;  w += (size_t)N_NODES * 64 * 4;       // 25.6 MB
    float* z2      = (float*)w;  w += (size_t)N_NODES * 16 * 4;       // 6.4 MB
    float* hw2r    = (float*)w;  w += (size_t)N_NODES * 16 * 4;       // 6.4 MB
    int*   deg     = (int*)w;    w += (size_t)N_NODES * 4;
    int*   row_ptr = (int*)w;    w += (size_t)(N_NODES + 1) * 4;
    int*   cursor  = (int*)w;    w += (size_t)N_NODES * 4;
    int*   bsum    = (int*)w;    w += 128 * 4;
    int*   boff    = (int*)w;

    hipMemsetAsync(deg, 0, (size_t)N_NODES * 4, stream);

    k_hist  <<<(N_EDGES + 255) / 256, 256, 0, stream>>>(ei, deg);
    k_scanA <<<NB_SCAN, 256, 0, stream>>>(deg, bsum);
    k_scanB <<<1, 64, 0, stream>>>(bsum, boff);
    k_scanC <<<NB_SCAN, 256, 0, stream>>>(deg, boff, row_ptr, cursor);
    k_fill  <<<(N_EDGES + 255) / 256, 256, 0, stream>>>(ei, ew, cursor, csr);
    k_gather<<<2048, 256, 0, stream>>>(x, row_ptr, csr, av);
    k_node  <<<1024, 512, 0, stream>>>(x, av, W1l, b1, W1r, W2l, W2r, z2, hw2r);
    k_l2    <<<1024, 256, 0, stream>>>(z2, row_ptr, csr, b2, hw2r, out);
}

// Round 14
// 462.246 us; speedup vs baseline: 2.0105x; 1.0504x over previous
//
#include <hip/hip_runtime.h>

#define N_NODES 100000
#define N_EDGES 1200000
#define NB_SCAN ((N_NODES + 1023) / 1024)   // 98 blocks of 1024 elements
// D_IN = D_HID = 64, D_OUT = 16
static_assert(N_NODES % 4 == 0, "k_node batches 4 nodes per wave");

// ---------------------------------------------------------------------------
// CSR build: deg histogram -> exclusive scan (3 tiny kernels) -> cursor fill.
// ---------------------------------------------------------------------------
__global__ __launch_bounds__(256) void k_hist(const int* __restrict__ ei,
                                              int* __restrict__ deg) {
    int e = blockIdx.x * 256 + threadIdx.x;
    if (e < N_EDGES) atomicAdd(&deg[ei[N_EDGES + e]], 1);
}

__global__ __launch_bounds__(256) void k_scanA(const int* __restrict__ deg,
                                               int* __restrict__ bsum) {
    const int b = blockIdx.x, t = threadIdx.x;
    const int base = b * 1024 + t * 4;
    int s = 0;
    #pragma unroll
    for (int i = 0; i < 4; ++i) {
        int idx = base + i;
        if (idx < N_NODES) s += deg[idx];
    }
    #pragma unroll
    for (int off = 1; off < 64; off <<= 1) s += __shfl_xor(s, off);
    __shared__ int part[4];
    if ((t & 63) == 0) part[t >> 6] = s;
    __syncthreads();
    if (t == 0) bsum[b] = part[0] + part[1] + part[2] + part[3];
}

__global__ void k_scanB(const int* __restrict__ bsum, int* __restrict__ boff) {
    if (threadIdx.x == 0) {
        int acc = 0;
        for (int i = 0; i < NB_SCAN; ++i) { boff[i] = acc; acc += bsum[i]; }
    }
}

__global__ __launch_bounds__(256) void k_scanC(const int* __restrict__ deg,
                                               const int* __restrict__ boff,
                                               int* __restrict__ row_ptr,
                                               int* __restrict__ cursor) {
    __shared__ int tot[256];
    const int b = blockIdx.x, t = threadIdx.x;
    const int base = b * 1024 + t * 4;
    int d[4]; int s = 0;
    #pragma unroll
    for (int i = 0; i < 4; ++i) {
        int idx = base + i;
        d[i] = (idx < N_NODES) ? deg[idx] : 0;
        s += d[i];
    }
    tot[t] = s;
    __syncthreads();
    for (int off = 1; off < 256; off <<= 1) {
        int v = (t >= off) ? tot[t - off] : 0;
        __syncthreads();
        tot[t] += v;
        __syncthreads();
    }
    int run = boff[b] + tot[t] - s;   // exclusive prefix for this thread
    #pragma unroll
    for (int i = 0; i < 4; ++i) {
        int idx = base + i;
        if (idx < N_NODES) { row_ptr[idx] = run; cursor[idx] = run; run += d[i]; }
    }
    if (b == 0 && t == 0) row_ptr[N_NODES] = N_EDGES;
}

__global__ __launch_bounds__(256) void k_fill(const int* __restrict__ ei,
                                              const float* __restrict__ ew,
                                              int* __restrict__ cursor,
                                              uint2* __restrict__ csr) {
    int e = blockIdx.x * 256 + threadIdx.x;
    if (e < N_EDGES) {
        int src = ei[e];
        int dst = ei[N_EDGES + e];
        int pos = atomicAdd(&cursor[dst], 1);
        csr[pos] = make_uint2((unsigned)src, __float_as_uint(ew[e]));
    }
}

// ---------------------------------------------------------------------------
// k_gather: av[n][d] = (sum_{in-edges} x[src][d]*w_e) / max(deg,1)
// Latency-bound phase at high occupancy: no LDS, low VGPR. Wave-uniform src
// row (readlane -> SGPR base) + lane-contiguous 256B load, ILP-4.
// NO min-waves clause: forcing it caused scratch spills (FETCH 1.5GB).
// ---------------------------------------------------------------------------
__global__ __launch_bounds__(256) void k_gather(const float* __restrict__ x,
                                                const int* __restrict__ row_ptr,
                                                const uint2* __restrict__ csr,
                                                float* __restrict__ av) {
    const int lane = threadIdx.x & 63;
    const int wid  = blockIdx.x * 4 + (threadIdx.x >> 6);
    const int nw   = gridDim.x * 4;
    for (int n = wid; n < N_NODES; n += nw) {
        const int r0 = row_ptr[n], r1 = row_ptr[n + 1];
        const int deg = r1 - r0;
        float acc0 = 0.f, acc1 = 0.f, acc2 = 0.f, acc3 = 0.f;
        for (int base = r0; base < r1; base += 64) {
            const int m = r1 - base < 64 ? r1 - base : 64;
            uint2 sw = make_uint2(0u, 0u);
            if (lane < m) sw = csr[base + lane];        // coalesced metadata
            const int sv = (int)sw.x;
            const int wv = (int)sw.y;
            int it = 0;
            for (; it + 4 <= m; it += 4) {
                int s0 = __builtin_amdgcn_readlane(sv, it);
                int s1 = __builtin_amdgcn_readlane(sv, it + 1);
                int s2 = __builtin_amdgcn_readlane(sv, it + 2);
                int s3 = __builtin_amdgcn_readlane(sv, it + 3);
                float w0 = __int_as_float(__builtin_amdgcn_readlane(wv, it));
                float w1 = __int_as_float(__builtin_amdgcn_readlane(wv, it + 1));
                float w2 = __int_as_float(__builtin_amdgcn_readlane(wv, it + 2));
                float w3 = __int_as_float(__builtin_amdgcn_readlane(wv, it + 3));
                // 4 independent wave-wide 256B gathers -> 4 outstanding loads
                float v0 = x[(size_t)s0 * 64 + lane];
                float v1 = x[(size_t)s1 * 64 + lane];
                float v2 = x[(size_t)s2 * 64 + lane];
                float v3 = x[(size_t)s3 * 64 + lane];
                acc0 = fmaf(v0, w0, acc0);
                acc1 = fmaf(v1, w1, acc1);
                acc2 = fmaf(v2, w2, acc2);
                acc3 = fmaf(v3, w3, acc3);
            }
            for (; it < m; ++it) {
                int   s = __builtin_amdgcn_readlane(sv, it);
                float w = __int_as_float(__builtin_amdgcn_readlane(wv, it));
                acc0 = fmaf(x[(size_t)s * 64 + lane], w, acc0);
            }
        }
        const float acc = (acc0 + acc1) + (acc2 + acc3);
        const float inv = 1.f / (float)(deg > 0 ? deg : 1);
        av[(size_t)n * 64 + lane] = acc * inv;          // coalesced 256B store
    }
}

// ---------------------------------------------------------------------------
// k_node: dense per-node compute, 4 NODES PER WAVE (lane = dim).
// LDS-throughput fix: (a) W1l/W1r interleaved as float2 -> one ds_read_b64
// per k, (b) 4 nodes per wave so each weight read feeds 4 FMA chains.
// readlane ONLY with wave-uniform k (h-loop: unrolled constant). The
// epilogue's k = g*16+i is LANE-DEPENDENT -> must use __shfl (ds_bpermute
// handles divergent indices; readlane with divergent idx reads group-0's
// lane for everyone — that was round-13's absmax=4.2 bug).
//   h[u] = relu(av[n] @ W1l + x[n] @ W1r + b1); z2 = h@W2l; hw2r = h@W2r
// ---------------------------------------------------------------------------
__global__ __launch_bounds__(512) void k_node(const float* __restrict__ x,
                                              const float* __restrict__ av,
                                              const float* __restrict__ W1l,
                                              const float* __restrict__ b1,
                                              const float* __restrict__ W1r,
                                              const float* __restrict__ W2l,
                                              const float* __restrict__ W2r,
                                              float* __restrict__ z2,
                                              float* __restrict__ hw2r) {
    __shared__ float2 w1s[64 * 64];  // w1s[k*64+d] = (W1l[k][d], W1r[k][d])
    __shared__ float  w2l[64 * 17];  // stride-17: 4-way bank conflict -> 2-way
    __shared__ float  w2r[64 * 17];
    for (int i = threadIdx.x; i < 64 * 64; i += 512)
        w1s[i] = make_float2(W1l[i], W1r[i]);
    for (int i = threadIdx.x; i < 64 * 16; i += 512) {
        int k = i >> 4, j = i & 15;
        w2l[k * 17 + j] = W2l[i];
        w2r[k * 17 + j] = W2r[i];
    }
    __syncthreads();
    const int lane = threadIdx.x & 63;
    const int wid  = blockIdx.x * 8 + (threadIdx.x >> 6);
    const int nw   = gridDim.x * 8;
    const int j = lane & 15, g = lane >> 4;
    const float b1v = b1[lane];
    for (int n0 = wid * 4; n0 < N_NODES; n0 += nw * 4) {
        float avv[4], xr[4], hacc[4];
        #pragma unroll
        for (int u = 0; u < 4; ++u) {
            avv[u]  = av[(size_t)(n0 + u) * 64 + lane];
            xr[u]   = x[(size_t)(n0 + u) * 64 + lane];
            hacc[u] = b1v;
        }
        #pragma unroll
        for (int k = 0; k < 64; ++k) {
            const float2 w = w1s[k * 64 + lane];    // one b64 read, 4 nodes
            #pragma unroll
            for (int u = 0; u < 4; ++u) {
                // k is an unrolled constant -> uniform: readlane is legal here
                float ak = __int_as_float(__builtin_amdgcn_readlane(__float_as_int(avv[u]), k));
                float xk = __int_as_float(__builtin_amdgcn_readlane(__float_as_int(xr[u]),  k));
                hacc[u] = fmaf(ak, w.x, hacc[u]);
                hacc[u] = fmaf(xk, w.y, hacc[u]);
            }
        }
        float hval[4];
        #pragma unroll
        for (int u = 0; u < 4; ++u) hval[u] = hacc[u] > 0.f ? hacc[u] : 0.f;

        // z2 = h @ W2l, hw2r = h @ W2r (16 outs; groups split k, xor-combine)
        float az[4] = {0.f, 0.f, 0.f, 0.f}, ar[4] = {0.f, 0.f, 0.f, 0.f};
        #pragma unroll
        for (int i = 0; i < 16; ++i) {
            const int   k  = g * 16 + i;            // LANE-DEPENDENT index
            const float wl = w2l[k * 17 + j];
            const float wr = w2r[k * 17 + j];
            #pragma unroll
            for (int u = 0; u < 4; ++u) {
                float hk = __shfl(hval[u], k);      // divergent idx -> shfl
                az[u] = fmaf(hk, wl, az[u]);
                ar[u] = fmaf(hk, wr, ar[u]);
            }
        }
        #pragma unroll
        for (int u = 0; u < 4; ++u) {
            az[u] += __shfl_xor(az[u], 16); az[u] += __shfl_xor(az[u], 32);
            ar[u] += __shfl_xor(ar[u], 16); ar[u] += __shfl_xor(ar[u], 32);
        }
        if (g == 0) {
            #pragma unroll
            for (int u = 0; u < 4; ++u) {
                z2[(size_t)(n0 + u) * 16 + j]   = az[u];
                hw2r[(size_t)(n0 + u) * 16 + j] = ar[u];
            }
        }
    }
}

// ---------------------------------------------------------------------------
// k_l2: fused layer-2 gather + epilogue (wave per dst node).
// 4 lane-groups of 16; group g owns edges r0+g+4t. Unroll-4 (clamped index +
// zero weight, statically indexed arrays) -> 16 outstanding 64B gathers/wave.
//   out[n][j] = (sum z2[src][j]*w)/max(deg,1) + b2[j] + hw2r[n][j]
// ---------------------------------------------------------------------------
__global__ __launch_bounds__(256) void k_l2(const float* __restrict__ z2,
                                            const int* __restrict__ row_ptr,
                                            const uint2* __restrict__ csr,
                                            const float* __restrict__ b2,
                                            const float* __restrict__ hw2r,
                                            float* __restrict__ out) {
    const int lane = threadIdx.x & 63;
    const int wid  = blockIdx.x * 4 + (threadIdx.x >> 6);
    const int nw   = gridDim.x * 4;
    const int j = lane & 15, g = lane >> 4;
    for (int n = wid; n < N_NODES; n += nw) {
        const int r0 = row_ptr[n], r1 = row_ptr[n + 1];
        const int deg = r1 - r0;
        const int rmax = r1 - 1;
        float a = 0.f;
        for (int i0 = r0 + g; i0 < r1; i0 += 16) {
            uint2 e[4]; float wt[4];
            #pragma unroll
            for (int u = 0; u < 4; ++u) {
                int idx = i0 + u * 4;
                int idc = idx < rmax ? idx : rmax;   // clamp: valid address
                e[u]  = csr[idc];
                wt[u] = (idx < r1) ? __uint_as_float(e[u].y) : 0.f;
            }
            float zv[4];
            #pragma unroll
            for (int u = 0; u < 4; ++u)
                zv[u] = z2[(size_t)e[u].x * 16 + j];
            #pragma unroll
            for (int u = 0; u < 4; ++u) a = fmaf(zv[u], wt[u], a);
        }
        a += __shfl_xor(a, 16); a += __shfl_xor(a, 32);
        if (g == 0) {
            const float inv = 1.f / (float)(deg > 0 ? deg : 1);
            out[(size_t)n * 16 + j] = a * inv + b2[j] + hw2r[(size_t)n * 16 + j];
        }
    }
}

extern "C" void kernel_launch(void* const* d_in, const int* in_sizes, int n_in,
                              void* d_out, int out_size, void* d_ws, size_t ws_size,
                              hipStream_t stream) {
    const float* x   = (const float*)d_in[0];
    const int*   ei  = (const int*)d_in[1];   // [2, E]: row0=src, row1=dst
    const float* ew  = (const float*)d_in[2];
    const float* W1l = (const float*)d_in[3];
    const float* b1  = (const float*)d_in[4];
    const float* W1r = (const float*)d_in[5];
    const float* W2l = (const float*)d_in[6];
    const float* b2  = (const float*)d_in[7];
    const float* W2r = (const float*)d_in[8];
    float* out = (float*)d_out;

    // Workspace layout (csr first: 8B alignment at base).
    char* w = (char*)d_ws;
    uint2* csr     = (uint2*)w;  w += (size_t)N_EDGES * 8;            // 9.6 MB
    float* av      = (float*)w;  w += (size_t)N_NODES * 64 * 4;       // 25.6 MB
    float* z2      = (float*)w;  w += (size_t)N_NODES * 16 * 4;       // 6.4 MB
    float* hw2r    = (float*)w;  w += (size_t)N_NODES * 16 * 4;       // 6.4 MB
    int*   deg     = (int*)w;    w += (size_t)N_NODES * 4;
    int*   row_ptr = (int*)w;    w += (size_t)(N_NODES + 1) * 4;
    int*   cursor  = (int*)w;    w += (size_t)N_NODES * 4;
    int*   bsum    = (int*)w;    w += 128 * 4;
    int*   boff    = (int*)w;

    hipMemsetAsync(deg, 0, (size_t)N_NODES * 4, stream);

    k_hist  <<<(N_EDGES + 255) / 256, 256, 0, stream>>>(ei, deg);
    k_scanA <<<NB_SCAN, 256, 0, stream>>>(deg, bsum);
    k_scanB <<<1, 64, 0, stream>>>(bsum, boff);
    k_scanC <<<NB_SCAN, 256, 0, stream>>>(deg, boff, row_ptr, cursor);
    k_fill  <<<(N_EDGES + 255) / 256, 256, 0, stream>>>(ei, ew, cursor, csr);
    k_gather<<<2048, 256, 0, stream>>>(x, row_ptr, csr, av);
    k_node  <<<1024, 512, 0, stream>>>(x, av, W1l, b1, W1r, W2l, W2r, z2, hw2r);
    k_l2    <<<1024, 256, 0, stream>>>(z2, row_ptr, csr, b2, hw2r, out);
}

// Round 15
// 457.663 us; speedup vs baseline: 2.0306x; 1.0100x over previous
//
#include <hip/hip_runtime.h>

#define N_NODES 100000
#define N_EDGES 1200000
#define NB_SCAN ((N_NODES + 1023) / 1024)   // 98 blocks of 1024 elements
// D_IN = D_HID = 64, D_OUT = 16
static_assert(N_NODES % 4 == 0, "k_node batches 4 nodes per wave");

// ---------------------------------------------------------------------------
// CSR build: deg histogram -> exclusive scan (3 tiny kernels) -> cursor fill.
// ---------------------------------------------------------------------------
__global__ __launch_bounds__(256) void k_hist(const int* __restrict__ ei,
                                              int* __restrict__ deg) {
    int e = blockIdx.x * 256 + threadIdx.x;
    if (e < N_EDGES) atomicAdd(&deg[ei[N_EDGES + e]], 1);
}

__global__ __launch_bounds__(256) void k_scanA(const int* __restrict__ deg,
                                               int* __restrict__ bsum) {
    const int b = blockIdx.x, t = threadIdx.x;
    const int base = b * 1024 + t * 4;
    int s = 0;
    #pragma unroll
    for (int i = 0; i < 4; ++i) {
        int idx = base + i;
        if (idx < N_NODES) s += deg[idx];
    }
    #pragma unroll
    for (int off = 1; off < 64; off <<= 1) s += __shfl_xor(s, off);
    __shared__ int part[4];
    if ((t & 63) == 0) part[t >> 6] = s;
    __syncthreads();
    if (t == 0) bsum[b] = part[0] + part[1] + part[2] + part[3];
}

__global__ void k_scanB(const int* __restrict__ bsum, int* __restrict__ boff) {
    if (threadIdx.x == 0) {
        int acc = 0;
        for (int i = 0; i < NB_SCAN; ++i) { boff[i] = acc; acc += bsum[i]; }
    }
}

__global__ __launch_bounds__(256) void k_scanC(const int* __restrict__ deg,
                                               const int* __restrict__ boff,
                                               int* __restrict__ row_ptr,
                                               int* __restrict__ cursor) {
    __shared__ int tot[256];
    const int b = blockIdx.x, t = threadIdx.x;
    const int base = b * 1024 + t * 4;
    int d[4]; int s = 0;
    #pragma unroll
    for (int i = 0; i < 4; ++i) {
        int idx = base + i;
        d[i] = (idx < N_NODES) ? deg[idx] : 0;
        s += d[i];
    }
    tot[t] = s;
    __syncthreads();
    for (int off = 1; off < 256; off <<= 1) {
        int v = (t >= off) ? tot[t - off] : 0;
        __syncthreads();
        tot[t] += v;
        __syncthreads();
    }
    int run = boff[b] + tot[t] - s;   // exclusive prefix for this thread
    #pragma unroll
    for (int i = 0; i < 4; ++i) {
        int idx = base + i;
        if (idx < N_NODES) { row_ptr[idx] = run; cursor[idx] = run; run += d[i]; }
    }
    if (b == 0 && t == 0) row_ptr[N_NODES] = N_EDGES;
}

__global__ __launch_bounds__(256) void k_fill(const int* __restrict__ ei,
                                              const float* __restrict__ ew,
                                              int* __restrict__ cursor,
                                              uint2* __restrict__ csr) {
    int e = blockIdx.x * 256 + threadIdx.x;
    if (e < N_EDGES) {
        int src = ei[e];
        int dst = ei[N_EDGES + e];
        int pos = atomicAdd(&cursor[dst], 1);
        csr[pos] = make_uint2((unsigned)src, __float_as_uint(ew[e]));
    }
}

// ---------------------------------------------------------------------------
// k_gather: av[n][d] = (sum_{in-edges} x[src][d]*w_e) / max(deg,1)
// Latency-bound phase at high occupancy: no LDS, low VGPR. Wave-uniform src
// row (readlane -> SGPR base) + lane-contiguous 256B load, ILP-4.
// NO min-waves clause: forcing it caused scratch spills (FETCH 1.5GB).
// ---------------------------------------------------------------------------
__global__ __launch_bounds__(256) void k_gather(const float* __restrict__ x,
                                                const int* __restrict__ row_ptr,
                                                const uint2* __restrict__ csr,
                                                float* __restrict__ av) {
    const int lane = threadIdx.x & 63;
    const int wid  = blockIdx.x * 4 + (threadIdx.x >> 6);
    const int nw   = gridDim.x * 4;
    for (int n = wid; n < N_NODES; n += nw) {
        const int r0 = row_ptr[n], r1 = row_ptr[n + 1];
        const int deg = r1 - r0;
        float acc0 = 0.f, acc1 = 0.f, acc2 = 0.f, acc3 = 0.f;
        for (int base = r0; base < r1; base += 64) {
            const int m = r1 - base < 64 ? r1 - base : 64;
            uint2 sw = make_uint2(0u, 0u);
            if (lane < m) sw = csr[base + lane];        // coalesced metadata
            const int sv = (int)sw.x;
            const int wv = (int)sw.y;
            int it = 0;
            for (; it + 4 <= m; it += 4) {
                int s0 = __builtin_amdgcn_readlane(sv, it);
                int s1 = __builtin_amdgcn_readlane(sv, it + 1);
                int s2 = __builtin_amdgcn_readlane(sv, it + 2);
                int s3 = __builtin_amdgcn_readlane(sv, it + 3);
                float w0 = __int_as_float(__builtin_amdgcn_readlane(wv, it));
                float w1 = __int_as_float(__builtin_amdgcn_readlane(wv, it + 1));
                float w2 = __int_as_float(__builtin_amdgcn_readlane(wv, it + 2));
                float w3 = __int_as_float(__builtin_amdgcn_readlane(wv, it + 3));
                // 4 independent wave-wide 256B gathers -> 4 outstanding loads
                float v0 = x[(size_t)s0 * 64 + lane];
                float v1 = x[(size_t)s1 * 64 + lane];
                float v2 = x[(size_t)s2 * 64 + lane];
                float v3 = x[(size_t)s3 * 64 + lane];
                acc0 = fmaf(v0, w0, acc0);
                acc1 = fmaf(v1, w1, acc1);
                acc2 = fmaf(v2, w2, acc2);
                acc3 = fmaf(v3, w3, acc3);
            }
            for (; it < m; ++it) {
                int   s = __builtin_amdgcn_readlane(sv, it);
                float w = __int_as_float(__builtin_amdgcn_readlane(wv, it));
                acc0 = fmaf(x[(size_t)s * 64 + lane], w, acc0);
            }
        }
        const float acc = (acc0 + acc1) + (acc2 + acc3);
        const float inv = 1.f / (float)(deg > 0 ? deg : 1);
        av[(size_t)n * 64 + lane] = acc * inv;          // coalesced 256B store
    }
}

// ---------------------------------------------------------------------------
// k_node: dense per-node compute, 4 NODES PER WAVE (lane = dim).
// LDS fix (round 14, confirmed): float2-interleaved W1 -> one ds_read_b64/k,
// 4 nodes/wave amortize each weight read over 4 FMA chains.
// Round-14 counters showed __launch_bounds__(512) defaulted to a 128-VGPR
// cap -> ~200MB scratch spill (WRITE 200MB vs 12.8MB logical). (512,1)
// raises the cap to 256 (block's 2 waves/SIMD must fit: 512/2): no spill.
// Occupancy ~8 waves/CU is fine — this kernel is VALU/LDS-bound, its inputs
// stream coalesced through L2.
// readlane ONLY with wave-uniform k (h-loop unrolled constant); the
// epilogue's k = g*16+i is lane-dependent -> __shfl (round-13 bug).
// ---------------------------------------------------------------------------
__global__ __launch_bounds__(512, 1) void k_node(const float* __restrict__ x,
                                                 const float* __restrict__ av,
                                                 const float* __restrict__ W1l,
                                                 const float* __restrict__ b1,
                                                 const float* __restrict__ W1r,
                                                 const float* __restrict__ W2l,
                                                 const float* __restrict__ W2r,
                                                 float* __restrict__ z2,
                                                 float* __restrict__ hw2r) {
    __shared__ float2 w1s[64 * 64];  // w1s[k*64+d] = (W1l[k][d], W1r[k][d])
    __shared__ float  w2l[64 * 17];  // stride-17: 4-way bank conflict -> 2-way
    __shared__ float  w2r[64 * 17];
    for (int i = threadIdx.x; i < 64 * 64; i += 512)
        w1s[i] = make_float2(W1l[i], W1r[i]);
    for (int i = threadIdx.x; i < 64 * 16; i += 512) {
        int k = i >> 4, j = i & 15;
        w2l[k * 17 + j] = W2l[i];
        w2r[k * 17 + j] = W2r[i];
    }
    __syncthreads();
    const int lane = threadIdx.x & 63;
    const int wid  = blockIdx.x * 8 + (threadIdx.x >> 6);
    const int nw   = gridDim.x * 8;
    const int j = lane & 15, g = lane >> 4;
    const float b1v = b1[lane];
    for (int n0 = wid * 4; n0 < N_NODES; n0 += nw * 4) {
        float avv[4], xr[4], hacc[4];
        #pragma unroll
        for (int u = 0; u < 4; ++u) {
            avv[u]  = av[(size_t)(n0 + u) * 64 + lane];
            xr[u]   = x[(size_t)(n0 + u) * 64 + lane];
            hacc[u] = b1v;
        }
        #pragma unroll
        for (int k = 0; k < 64; ++k) {
            const float2 w = w1s[k * 64 + lane];    // one b64 read, 4 nodes
            #pragma unroll
            for (int u = 0; u < 4; ++u) {
                // k is an unrolled constant -> uniform: readlane is legal here
                float ak = __int_as_float(__builtin_amdgcn_readlane(__float_as_int(avv[u]), k));
                float xk = __int_as_float(__builtin_amdgcn_readlane(__float_as_int(xr[u]),  k));
                hacc[u] = fmaf(ak, w.x, hacc[u]);
                hacc[u] = fmaf(xk, w.y, hacc[u]);
            }
        }
        float hval[4];
        #pragma unroll
        for (int u = 0; u < 4; ++u) hval[u] = hacc[u] > 0.f ? hacc[u] : 0.f;

        // z2 = h @ W2l, hw2r = h @ W2r (16 outs; groups split k, xor-combine)
        float az[4] = {0.f, 0.f, 0.f, 0.f}, ar[4] = {0.f, 0.f, 0.f, 0.f};
        #pragma unroll
        for (int i = 0; i < 16; ++i) {
            const int   k  = g * 16 + i;            // LANE-DEPENDENT index
            const float wl = w2l[k * 17 + j];
            const float wr = w2r[k * 17 + j];
            #pragma unroll
            for (int u = 0; u < 4; ++u) {
                float hk = __shfl(hval[u], k);      // divergent idx -> shfl
                az[u] = fmaf(hk, wl, az[u]);
                ar[u] = fmaf(hk, wr, ar[u]);
            }
        }
        #pragma unroll
        for (int u = 0; u < 4; ++u) {
            az[u] += __shfl_xor(az[u], 16); az[u] += __shfl_xor(az[u], 32);
            ar[u] += __shfl_xor(ar[u], 16); ar[u] += __shfl_xor(ar[u], 32);
        }
        if (g == 0) {
            #pragma unroll
            for (int u = 0; u < 4; ++u) {
                z2[(size_t)(n0 + u) * 16 + j]   = az[u];
                hw2r[(size_t)(n0 + u) * 16 + j] = ar[u];
            }
        }
    }
}

// ---------------------------------------------------------------------------
// k_l2: fused layer-2 gather + epilogue (wave per dst node).
// 4 lane-groups of 16; group g owns edges r0+g+4t. Unroll-4 (clamped index +
// zero weight, statically indexed arrays) -> 16 outstanding 64B gathers/wave.
//   out[n][j] = (sum z2[src][j]*w)/max(deg,1) + b2[j] + hw2r[n][j]
// ---------------------------------------------------------------------------
__global__ __launch_bounds__(256) void k_l2(const float* __restrict__ z2,
                                            const int* __restrict__ row_ptr,
                                            const uint2* __restrict__ csr,
                                            const float* __restrict__ b2,
                                            const float* __restrict__ hw2r,
                                            float* __restrict__ out) {
    const int lane = threadIdx.x & 63;
    const int wid  = blockIdx.x * 4 + (threadIdx.x >> 6);
    const int nw   = gridDim.x * 4;
    const int j = lane & 15, g = lane >> 4;
    for (int n = wid; n < N_NODES; n += nw) {
        const int r0 = row_ptr[n], r1 = row_ptr[n + 1];
        const int deg = r1 - r0;
        const int rmax = r1 - 1;
        float a = 0.f;
        for (int i0 = r0 + g; i0 < r1; i0 += 16) {
            uint2 e[4]; float wt[4];
            #pragma unroll
            for (int u = 0; u < 4; ++u) {
                int idx = i0 + u * 4;
                int idc = idx < rmax ? idx : rmax;   // clamp: valid address
                e[u]  = csr[idc];
                wt[u] = (idx < r1) ? __uint_as_float(e[u].y) : 0.f;
            }
            float zv[4];
            #pragma unroll
            for (int u = 0; u < 4; ++u)
                zv[u] = z2[(size_t)e[u].x * 16 + j];
            #pragma unroll
            for (int u = 0; u < 4; ++u) a = fmaf(zv[u], wt[u], a);
        }
        a += __shfl_xor(a, 16); a += __shfl_xor(a, 32);
        if (g == 0) {
            const float inv = 1.f / (float)(deg > 0 ? deg : 1);
            out[(size_t)n * 16 + j] = a * inv + b2[j] + hw2r[(size_t)n * 16 + j];
        }
    }
}

extern "C" void kernel_launch(void* const* d_in, const int* in_sizes, int n_in,
                              void* d_out, int out_size, void* d_ws, size_t ws_size,
                              hipStream_t stream) {
    const float* x   = (const float*)d_in[0];
    const int*   ei  = (const int*)d_in[1];   // [2, E]: row0=src, row1=dst
    const float* ew  = (const float*)d_in[2];
    const float* W1l = (const float*)d_in[3];
    const float* b1  = (const float*)d_in[4];
    const float* W1r = (const float*)d_in[5];
    const float* W2l = (const float*)d_in[6];
    const float* b2  = (const float*)d_in[7];
    const float* W2r = (const float*)d_in[8];
    float* out = (float*)d_out;

    // Workspace layout (csr first: 8B alignment at base).
    char* w = (char*)d_ws;
    uint2* csr     = (uint2*)w;  w += (size_t)N_EDGES * 8;            // 9.6 MB
    float* av      = (float*)w;  w += (size_t)N_NODES * 64 * 4;       // 25.6 MB
    float* z2      = (float*)w;  w += (size_t)N_NODES * 16 * 4;       // 6.4 MB
    float* hw2r    = (float*)w;  w += (size_t)N_NODES * 16 * 4;       // 6.4 MB
    int*   deg     = (int*)w;    w += (size_t)N_NODES * 4;
    int*   row_ptr = (int*)w;    w += (size_t)(N_NODES + 1) * 4;
    int*   cursor  = (int*)w;    w += (size_t)N_NODES * 4;
    int*   bsum    = (int*)w;    w += 128 * 4;
    int*   boff    = (int*)w;

    hipMemsetAsync(deg, 0, (size_t)N_NODES * 4, stream);

    k_hist  <<<(N_EDGES + 255) / 256, 256, 0, stream>>>(ei, deg);
    k_scanA <<<NB_SCAN, 256, 0, stream>>>(deg, bsum);
    k_scanB <<<1, 64, 0, stream>>>(bsum, boff);
    k_scanC <<<NB_SCAN, 256, 0, stream>>>(deg, boff, row_ptr, cursor);
    k_fill  <<<(N_EDGES + 255) / 256, 256, 0, stream>>>(ei, ew, cursor, csr);
    k_gather<<<2048, 256, 0, stream>>>(x, row_ptr, csr, av);
    k_node  <<<1024, 512, 0, stream>>>(x, av, W1l, b1, W1r, W2l, W2r, z2, hw2r);
    k_l2    <<<1024, 256, 0, stream>>>(z2, row_ptr, csr, b2, hw2r, out);
}